// Round 2
// baseline (542.084 us; speedup 1.0000x reference)
//
#include <hip/hip_runtime.h>
#include <hip/hip_bf16.h>

// MolecularGraphNet: 3x SAGEConv(mean) + Linear, on MI355X.
// Strategy:
//  - edge_index arrives as int32 (harness converts int64 -> int32).
//  - Build CSR (dst -> list of src) on device each launch.
//  - Aggregation at the cheaper dimension (pre-multiply): mean(x) for L1 (256),
//    mean(h1) (512) for L2, mean(h2) (512) for L3.
//  - Each SAGE layer = ONE bf16 MFMA GEMM: A = [mean | h] (K concat),
//    B^T = [Wl; Wr] transposed to [N_out, K] at launch (weights tiny).
//  - GEMM: 128x128 tile, 4 waves (each 64x64 = 4x4 of 16x16x32 MFMA), LDS staged.
//  - H3 aliases Acat2 (dead after GEMM2) to keep ws usage ~108 MB.

typedef __bf16 bf16x8 __attribute__((ext_vector_type(8)));
typedef float  f32x4  __attribute__((ext_vector_type(4)));

#define N_NODES 20000
#define N_EDGES 320000

__device__ __forceinline__ int clampi(int v, int lo, int hi) {
    return v < lo ? lo : (v > hi ? hi : v);
}

// ---------------- CSR build ----------------

__global__ void k_count(const int* __restrict__ ei, int E, int* __restrict__ cnt) {
    int e = blockIdx.x * blockDim.x + threadIdx.x;
    if (e < E) {
        int dst = clampi(ei[E + e], 0, N_NODES - 1);
        atomicAdd(&cnt[dst], 1);
    }
}

__global__ __launch_bounds__(1024) void k_scan(const int* __restrict__ cnt,
                                               int* __restrict__ off,
                                               int* __restrict__ cur, int n) {
    __shared__ int sm[1024];
    __shared__ int carry_s;
    int tid = threadIdx.x;
    if (tid == 0) carry_s = 0;
    __syncthreads();
    int nloops = (n + 1023) / 1024;
    for (int it = 0; it < nloops; ++it) {
        int i = it * 1024 + tid;
        int v = (i < n) ? cnt[i] : 0;
        sm[tid] = v;
        __syncthreads();
        for (int s = 1; s < 1024; s <<= 1) {
            int t = (tid >= s) ? sm[tid - s] : 0;
            __syncthreads();
            sm[tid] += t;
            __syncthreads();
        }
        int excl = sm[tid] - v;
        int c = carry_s;
        if (i < n) { off[i] = c + excl; cur[i] = c + excl; }
        __syncthreads();
        if (tid == 1023) carry_s = c + sm[1023];
        __syncthreads();
    }
    if (tid == 0) off[n] = carry_s;
}

__global__ void k_fill(const int* __restrict__ ei, int E,
                       int* __restrict__ cur, int* __restrict__ csr) {
    int e = blockIdx.x * blockDim.x + threadIdx.x;
    if (e < E) {
        int dst = clampi(ei[E + e], 0, N_NODES - 1);
        int src = clampi(ei[e], 0, N_NODES - 1);
        int pos = atomicAdd(&cur[dst], 1);
        if (pos >= 0 && pos < E) csr[pos] = src;
    }
}

// ---------------- converts / transposes ----------------

// x fp32 [N,256] -> bf16 into Acat1 columns 256..511 (row stride 512)
__global__ void k_convert_x(const float* __restrict__ x, __hip_bfloat16* __restrict__ acat) {
    int i = blockIdx.x * blockDim.x + threadIdx.x;   // pair index over N*128
    if (i >= N_NODES * 128) return;
    int node = i >> 7;
    int f2 = i & 127;
    float2 v = *(const float2*)(x + (size_t)node * 256 + f2 * 2);
    __hip_bfloat162 o;
    o.x = __float2bfloat16(v.x);
    o.y = __float2bfloat16(v.y);
    *(__hip_bfloat162*)(acat + (size_t)node * 512 + 256 + f2 * 2) = o;
}

// W fp32 [K,N] -> Wt bf16 [N, ldt], Wt[n][koff+k] = W[k][n]
__global__ void k_transpose_w(const float* __restrict__ W, int K, int N,
                              __hip_bfloat16* __restrict__ Wt, int ldt, int koff) {
    __shared__ float tile[32][33];
    int kb = blockIdx.y * 32, nb = blockIdx.x * 32;
    for (int i = 0; i < 32; i += 8) {
        int k = kb + threadIdx.y + i, n = nb + threadIdx.x;
        tile[threadIdx.y + i][threadIdx.x] = W[(size_t)k * N + n];
    }
    __syncthreads();
    for (int i = 0; i < 32; i += 8) {
        int n = nb + threadIdx.y + i, k = kb + threadIdx.x;
        Wt[(size_t)n * ldt + koff + k] = __float2bfloat16(tile[threadIdx.x][threadIdx.y + i]);
    }
}

// ---------------- aggregation (CSR gather, mean) ----------------

// layer 1: fp32 input [N,256]; out bf16 (cols 0..255 of stride-512 rows)
__global__ __launch_bounds__(256) void k_agg_f32(const float* __restrict__ xin,
                                                 const int* __restrict__ off,
                                                 const int* __restrict__ csr,
                                                 __hip_bfloat16* __restrict__ outp,
                                                 int ostride) {
    int node = blockIdx.x;
    int f = threadIdx.x;   // 256 threads, 1 col each
    int beg = off[node], end = off[node + 1];
    float acc = 0.f;
    int e = beg;
    for (; e + 4 <= end; e += 4) {
        int s0 = csr[e], s1 = csr[e + 1], s2 = csr[e + 2], s3 = csr[e + 3];
        float v0 = xin[(size_t)s0 * 256 + f];
        float v1 = xin[(size_t)s1 * 256 + f];
        float v2 = xin[(size_t)s2 * 256 + f];
        float v3 = xin[(size_t)s3 * 256 + f];
        acc += (v0 + v1) + (v2 + v3);
    }
    for (; e < end; ++e) acc += xin[(size_t)csr[e] * 256 + f];
    float c = fmaxf((float)(end - beg), 1.f);
    outp[(size_t)node * ostride + f] = __float2bfloat16(acc / c);
}

// layers 2/3: bf16 input rows of 512 feats (stride istride); out bf16 cols 0..511
__global__ __launch_bounds__(256) void k_agg_bf16(const __hip_bfloat16* __restrict__ hin,
                                                  int istride,
                                                  const int* __restrict__ off,
                                                  const int* __restrict__ csr,
                                                  __hip_bfloat16* __restrict__ outp,
                                                  int ostride) {
    int node = blockIdx.x;
    int f2 = threadIdx.x;  // 256 threads, 2 cols each
    int beg = off[node], end = off[node + 1];
    float a0 = 0.f, a1 = 0.f;
    int e = beg;
    for (; e + 4 <= end; e += 4) {
        int s0 = csr[e], s1 = csr[e + 1], s2 = csr[e + 2], s3 = csr[e + 3];
        __hip_bfloat162 v0 = *(const __hip_bfloat162*)(hin + (size_t)s0 * istride + f2 * 2);
        __hip_bfloat162 v1 = *(const __hip_bfloat162*)(hin + (size_t)s1 * istride + f2 * 2);
        __hip_bfloat162 v2 = *(const __hip_bfloat162*)(hin + (size_t)s2 * istride + f2 * 2);
        __hip_bfloat162 v3 = *(const __hip_bfloat162*)(hin + (size_t)s3 * istride + f2 * 2);
        a0 += (__bfloat162float(v0.x) + __bfloat162float(v1.x)) +
              (__bfloat162float(v2.x) + __bfloat162float(v3.x));
        a1 += (__bfloat162float(v0.y) + __bfloat162float(v1.y)) +
              (__bfloat162float(v2.y) + __bfloat162float(v3.y));
    }
    for (; e < end; ++e) {
        __hip_bfloat162 v = *(const __hip_bfloat162*)(hin + (size_t)csr[e] * istride + f2 * 2);
        a0 += __bfloat162float(v.x);
        a1 += __bfloat162float(v.y);
    }
    float c = fmaxf((float)(end - beg), 1.f);
    __hip_bfloat162 o;
    o.x = __float2bfloat16(a0 / c);
    o.y = __float2bfloat16(a1 / c);
    *(__hip_bfloat162*)(outp + (size_t)node * ostride + f2 * 2) = o;
}

// ---------------- bf16 MFMA GEMM: C = act(A @ Bt^T + bias) ----------------
// A: [M,K] bf16 row-major (lda); Bt: [N,K] bf16 row-major; N % 128 == 0, K % 32 == 0.
// Output: bf16 (ldc, col offset coff) or fp32.

template <bool RELU, bool OUT_BF16>
__global__ __launch_bounds__(256) void k_gemm_bt(const __hip_bfloat16* __restrict__ A,
                                                 int lda, int M, int K,
                                                 const __hip_bfloat16* __restrict__ Bt,
                                                 const float* __restrict__ bias,
                                                 __hip_bfloat16* __restrict__ obf,
                                                 float* __restrict__ of32,
                                                 int ldc, int coff) {
    __shared__ __hip_bfloat16 Alds[128 * 32];
    __shared__ __hip_bfloat16 Blds[128 * 32];

    int tid = threadIdx.x;
    int wave = tid >> 6, lane = tid & 63;
    int wr = wave >> 1, wc = wave & 1;      // 2x2 wave grid, each wave 64x64
    int quad = lane >> 4, l16 = lane & 15;

    int row0 = blockIdx.x * 128;
    int col0 = blockIdx.y * 128;

    f32x4 acc[4][4] = {};

    int srow = tid >> 2;            // 0..63
    int scol = (tid & 3) * 8;       // 0,8,16,24

    for (int k0 = 0; k0 < K; k0 += 32) {
        __syncthreads();
        // stage A (128x32) and Bt (128x32), 16B per thread per half
        for (int half = 0; half < 2; ++half) {
            int r = srow + half * 64;
            int gr = row0 + r;
            uint4 va = make_uint4(0u, 0u, 0u, 0u);
            if (gr < M) va = *(const uint4*)(A + (size_t)gr * lda + k0 + scol);
            *(uint4*)(&Alds[r * 32 + scol]) = va;
            int gn = col0 + r;
            uint4 vb = *(const uint4*)(Bt + (size_t)gn * K + k0 + scol);
            *(uint4*)(&Blds[r * 32 + scol]) = vb;
        }
        __syncthreads();

        const __bf16* Ab = (const __bf16*)Alds;
        const __bf16* Bb = (const __bf16*)Blds;
        bf16x8 af[4], bf[4];
#pragma unroll
        for (int mi = 0; mi < 4; ++mi)
            af[mi] = *(const bf16x8*)(Ab + (wr * 64 + mi * 16 + l16) * 32 + quad * 8);
#pragma unroll
        for (int ni = 0; ni < 4; ++ni)
            bf[ni] = *(const bf16x8*)(Bb + (wc * 64 + ni * 16 + l16) * 32 + quad * 8);
#pragma unroll
        for (int mi = 0; mi < 4; ++mi)
#pragma unroll
            for (int ni = 0; ni < 4; ++ni)
                acc[mi][ni] = __builtin_amdgcn_mfma_f32_16x16x32_bf16(af[mi], bf[ni],
                                                                      acc[mi][ni], 0, 0, 0);
    }

    // epilogue: C/D layout col = lane&15, row = quad*4 + reg
#pragma unroll
    for (int ni = 0; ni < 4; ++ni) {
        int col = col0 + wc * 64 + ni * 16 + l16;
        float bv = bias[col];
#pragma unroll
        for (int mi = 0; mi < 4; ++mi) {
            int rbase = row0 + wr * 64 + mi * 16 + quad * 4;
#pragma unroll
            for (int r = 0; r < 4; ++r) {
                int row = rbase + r;
                if (row < M) {
                    float v = acc[mi][ni][r] + bv;
                    if (RELU) v = fmaxf(v, 0.f);
                    if (OUT_BF16)
                        obf[(size_t)row * ldc + coff + col] = __float2bfloat16(v);
                    else
                        of32[(size_t)row * ldc + coff + col] = v;
                }
            }
        }
    }
}

// ---------------- launch ----------------

extern "C" void kernel_launch(void* const* d_in, const int* in_sizes, int n_in,
                              void* d_out, int out_size, void* d_ws, size_t ws_size,
                              hipStream_t stream) {
    const float* x   = (const float*)d_in[0];
    const int*   ei  = (const int*)d_in[1];     // int64 in reference -> int32 here
    const float* Wl1 = (const float*)d_in[2];
    const float* bl1 = (const float*)d_in[3];
    const float* Wr1 = (const float*)d_in[4];
    const float* Wl2 = (const float*)d_in[5];
    const float* bl2 = (const float*)d_in[6];
    const float* Wr2 = (const float*)d_in[7];
    const float* Wl3 = (const float*)d_in[8];
    const float* bl3 = (const float*)d_in[9];
    const float* Wr3 = (const float*)d_in[10];
    const float* Wfc = (const float*)d_in[11];
    const float* bfc = (const float*)d_in[12];
    float* out = (float*)d_out;

    const int NN = N_NODES, E = N_EDGES;

    char* p = (char*)d_ws;
    auto alloc = [&](size_t bytes) {
        char* r = p;
        p += (bytes + 511) & ~(size_t)511;
        return r;
    };
    int* cnt = (int*)alloc((size_t)NN * 4);
    int* off = (int*)alloc((size_t)(NN + 1) * 4);
    int* cur = (int*)alloc((size_t)NN * 4);
    int* csr = (int*)alloc((size_t)E * 4);
    __hip_bfloat16* Acat1 = (__hip_bfloat16*)alloc((size_t)NN * 512 * 2);   // [mean(x)|x]
    __hip_bfloat16* Acat2 = (__hip_bfloat16*)alloc((size_t)NN * 1024 * 2);  // [mean(h1)|h1]
    __hip_bfloat16* Acat3 = (__hip_bfloat16*)alloc((size_t)NN * 1024 * 2);  // [mean(h2)|h2]
    __hip_bfloat16* Wt1 = (__hip_bfloat16*)alloc((size_t)512 * 512 * 2);    // [512n,512k]
    __hip_bfloat16* Wt2 = (__hip_bfloat16*)alloc((size_t)512 * 1024 * 2);   // [512n,1024k]
    __hip_bfloat16* Wt3 = (__hip_bfloat16*)alloc((size_t)1024 * 1024 * 2);  // [1024n,1024k]
    __hip_bfloat16* Wt4 = (__hip_bfloat16*)alloc((size_t)512 * 1024 * 2);   // [512n,1024k]
    __hip_bfloat16* H3 = Acat2;  // alias: Acat2 dead after GEMM2 (saves 41 MB)

    // CSR build
    hipMemsetAsync(cnt, 0, (size_t)NN * 4, stream);
    k_count<<<(E + 255) / 256, 256, 0, stream>>>(ei, E, cnt);
    k_scan<<<1, 1024, 0, stream>>>(cnt, off, cur, NN);
    k_fill<<<(E + 255) / 256, 256, 0, stream>>>(ei, E, cur, csr);

    // weight transposes (fp32 -> bf16, [K,N] -> [N,Kcat])
    dim3 tb(32, 8);
    k_transpose_w<<<dim3(512 / 32, 256 / 32), tb, 0, stream>>>(Wl1, 256, 512, Wt1, 512, 0);
    k_transpose_w<<<dim3(512 / 32, 256 / 32), tb, 0, stream>>>(Wr1, 256, 512, Wt1, 512, 256);
    k_transpose_w<<<dim3(512 / 32, 512 / 32), tb, 0, stream>>>(Wl2, 512, 512, Wt2, 1024, 0);
    k_transpose_w<<<dim3(512 / 32, 512 / 32), tb, 0, stream>>>(Wr2, 512, 512, Wt2, 1024, 512);
    k_transpose_w<<<dim3(1024 / 32, 512 / 32), tb, 0, stream>>>(Wl3, 512, 1024, Wt3, 1024, 0);
    k_transpose_w<<<dim3(1024 / 32, 512 / 32), tb, 0, stream>>>(Wr3, 512, 1024, Wt3, 1024, 512);
    k_transpose_w<<<dim3(512 / 32, 1024 / 32), tb, 0, stream>>>(Wfc, 1024, 512, Wt4, 1024, 0);

    // x -> bf16 (right half of Acat1)
    k_convert_x<<<(NN * 128 + 255) / 256, 256, 0, stream>>>(x, Acat1);

    int mtiles = (NN + 127) / 128;  // 157

    // Layer 1
    k_agg_f32<<<NN, 256, 0, stream>>>(x, off, csr, Acat1, 512);
    k_gemm_bt<true, true><<<dim3(mtiles, 4), 256, 0, stream>>>(
        Acat1, 512, NN, 512, Wt1, bl1, Acat2, nullptr, 1024, 512);

    // Layer 2
    k_agg_bf16<<<NN, 256, 0, stream>>>(Acat2 + 512, 1024, off, csr, Acat2, 1024);
    k_gemm_bt<true, true><<<dim3(mtiles, 4), 256, 0, stream>>>(
        Acat2, 1024, NN, 1024, Wt2, bl2, Acat3, nullptr, 1024, 512);

    // Layer 3 (writes H3 == Acat2; GEMM3 reads only Acat3)
    k_agg_bf16<<<NN, 256, 0, stream>>>(Acat3 + 512, 1024, off, csr, Acat3, 1024);
    k_gemm_bt<true, true><<<dim3(mtiles, 8), 256, 0, stream>>>(
        Acat3, 1024, NN, 1024, Wt3, bl3, H3, nullptr, 1024, 0);

    // FC (fp32 out, no relu)
    k_gemm_bt<false, false><<<dim3(mtiles, 4), 256, 0, stream>>>(
        H3, 1024, NN, 1024, Wt4, bfc, nullptr, out, 512, 0);
}

// Round 3
// 522.222 us; speedup vs baseline: 1.0380x; 1.0380x over previous
//
#include <hip/hip_runtime.h>
#include <hip/hip_bf16.h>

// MolecularGraphNet: 3x SAGEConv(mean) + Linear, on MI355X.
//  - CSR build on device (int32 edge_index), 3-kernel parallel scan.
//  - Aggregation at the cheap dim with 16 B/lane gathers (4 rows in flight).
//  - Each SAGE layer = ONE bf16 MFMA GEMM over K-concat [mean | h].
//  - GEMM: 128x128 tile, col-tiles fastest in dispatch (A fetched once from HBM),
//    LDS row stride padded to 40 bf16 (80 B) to kill b128 bank-group conflicts.

typedef __bf16 bf16x8 __attribute__((ext_vector_type(8)));
typedef float  f32x4  __attribute__((ext_vector_type(4)));

#define N_NODES 20000
#define N_EDGES 320000
#define LDSS 40   // LDS row stride in bf16 (80 B; 5 bank-groups step, coprime w/ 8)

__device__ __forceinline__ int clampi(int v, int lo, int hi) {
    return v < lo ? lo : (v > hi ? hi : v);
}

// ---------------- CSR build ----------------

__global__ void k_count(const int* __restrict__ ei, int E, int* __restrict__ cnt) {
    int e = blockIdx.x * blockDim.x + threadIdx.x;
    if (e < E) {
        int dst = clampi(ei[E + e], 0, N_NODES - 1);
        atomicAdd(&cnt[dst], 1);
    }
}

__global__ __launch_bounds__(1024) void k_scan_block(const int* __restrict__ cnt,
                                                     int* __restrict__ off,
                                                     int* __restrict__ bsum, int n) {
    __shared__ int sm[1024];
    int b = blockIdx.x, tid = threadIdx.x;
    int i = b * 1024 + tid;
    int v = (i < n) ? cnt[i] : 0;
    sm[tid] = v;
    __syncthreads();
    for (int s = 1; s < 1024; s <<= 1) {
        int t = (tid >= s) ? sm[tid - s] : 0;
        __syncthreads();
        sm[tid] += t;
        __syncthreads();
    }
    if (i < n) off[i] = sm[tid] - v;   // exclusive, no carry yet
    if (tid == 1023) bsum[b] = sm[1023];
}

__global__ void k_scan_carry(const int* __restrict__ bsum, int* __restrict__ carry,
                             int nb, int* __restrict__ off, int n) {
    if (threadIdx.x == 0 && blockIdx.x == 0) {
        int acc = 0;
        for (int b = 0; b < nb; ++b) { carry[b] = acc; acc += bsum[b]; }
        off[n] = acc;
    }
}

__global__ __launch_bounds__(1024) void k_scan_add(int* __restrict__ off,
                                                   int* __restrict__ cur,
                                                   const int* __restrict__ carry, int n) {
    int i = blockIdx.x * 1024 + threadIdx.x;
    if (i < n) {
        int v = off[i] + carry[blockIdx.x];
        off[i] = v;
        cur[i] = v;
    }
}

__global__ void k_fill(const int* __restrict__ ei, int E,
                       int* __restrict__ cur, int* __restrict__ csr) {
    int e = blockIdx.x * blockDim.x + threadIdx.x;
    if (e < E) {
        int dst = clampi(ei[E + e], 0, N_NODES - 1);
        int src = clampi(ei[e], 0, N_NODES - 1);
        int pos = atomicAdd(&cur[dst], 1);
        if (pos >= 0 && pos < E) csr[pos] = src;
    }
}

// ---------------- weight transpose: W fp32 [K,N] -> Wt bf16 [N, ldt] ----------------

__global__ void k_transpose_w(const float* __restrict__ W, int K, int N,
                              __hip_bfloat16* __restrict__ Wt, int ldt, int koff) {
    __shared__ float tile[32][33];
    int kb = blockIdx.y * 32, nb = blockIdx.x * 32;
    for (int i = 0; i < 32; i += 8) {
        int k = kb + threadIdx.y + i, n = nb + threadIdx.x;
        tile[threadIdx.y + i][threadIdx.x] = W[(size_t)k * N + n];
    }
    __syncthreads();
    for (int i = 0; i < 32; i += 8) {
        int n = nb + threadIdx.y + i, k = kb + threadIdx.x;
        Wt[(size_t)n * ldt + koff + k] = __float2bfloat16(tile[threadIdx.x][threadIdx.y + i]);
    }
}

// ---------------- aggregation (CSR gather, mean) ----------------
// 4 row-slots x 64 lanes, 16 B/lane gathers, LDS cross-slot reduce.

// layer 1: fp32 input [N,256]; writes mean -> cols 0..255 AND own-row bf16 -> cols 256..511
__global__ __launch_bounds__(256) void k_agg_f32(const float* __restrict__ xin,
                                                 const int* __restrict__ off,
                                                 const int* __restrict__ csr,
                                                 __hip_bfloat16* __restrict__ outp,
                                                 int ostride) {
    __shared__ float sm[4][256];
    int node = blockIdx.x;
    int tid = threadIdx.x;
    int slot = tid >> 6, lane = tid & 63;
    int c0 = lane * 4;
    int beg = off[node], end = off[node + 1];
    float a0 = 0.f, a1 = 0.f, a2 = 0.f, a3 = 0.f;
    for (int e = beg + slot; e < end; e += 4) {
        int s = csr[e];
        float4 v = *(const float4*)(xin + (size_t)s * 256 + c0);
        a0 += v.x; a1 += v.y; a2 += v.z; a3 += v.w;
    }
    sm[slot][c0] = a0; sm[slot][c0 + 1] = a1; sm[slot][c0 + 2] = a2; sm[slot][c0 + 3] = a3;
    __syncthreads();
    float inv = 1.f / fmaxf((float)(end - beg), 1.f);
    float r = (sm[0][tid] + sm[1][tid]) + (sm[2][tid] + sm[3][tid]);
    outp[(size_t)node * ostride + tid] = __float2bfloat16(r * inv);
    // fused x -> bf16 convert (right half of concat row)
    outp[(size_t)node * ostride + 256 + tid] = __float2bfloat16(xin[(size_t)node * 256 + tid]);
}

// layers 2/3: bf16 input rows of 512 feats (stride istride); out bf16 cols 0..511
__global__ __launch_bounds__(256) void k_agg_bf16(const __hip_bfloat16* __restrict__ hin,
                                                  int istride,
                                                  const int* __restrict__ off,
                                                  const int* __restrict__ csr,
                                                  __hip_bfloat16* __restrict__ outp,
                                                  int ostride) {
    __shared__ float sm[4][512];
    int node = blockIdx.x;
    int tid = threadIdx.x;
    int slot = tid >> 6, lane = tid & 63;
    int c0 = lane * 8;
    int beg = off[node], end = off[node + 1];
    float a[8] = {};
    for (int e = beg + slot; e < end; e += 4) {
        int s = csr[e];
        uint4 v = *(const uint4*)(hin + (size_t)s * istride + c0);
        const __hip_bfloat16* hb = (const __hip_bfloat16*)&v;
#pragma unroll
        for (int j = 0; j < 8; ++j) a[j] += __bfloat162float(hb[j]);
    }
#pragma unroll
    for (int j = 0; j < 8; ++j) sm[slot][c0 + j] = a[j];
    __syncthreads();
    float inv = 1.f / fmaxf((float)(end - beg), 1.f);
    int c = tid * 2;
    float r0 = (sm[0][c] + sm[1][c]) + (sm[2][c] + sm[3][c]);
    float r1 = (sm[0][c + 1] + sm[1][c + 1]) + (sm[2][c + 1] + sm[3][c + 1]);
    __hip_bfloat162 o;
    o.x = __float2bfloat16(r0 * inv);
    o.y = __float2bfloat16(r1 * inv);
    *(__hip_bfloat162*)(outp + (size_t)node * ostride + c) = o;
}

// ---------------- bf16 MFMA GEMM: C = act(A @ Bt^T + bias) ----------------
// A: [M,K] bf16 row-major (lda); Bt: [N,K] bf16 row-major; N % 128 == 0, K % 32 == 0.
// Grid: (col_tiles, row_tiles) -- col fastest so A row-tiles are fetched once.

template <bool RELU, bool OUT_BF16>
__global__ __launch_bounds__(256) void k_gemm_bt(const __hip_bfloat16* __restrict__ A,
                                                 int lda, int M, int K,
                                                 const __hip_bfloat16* __restrict__ Bt,
                                                 const float* __restrict__ bias,
                                                 __hip_bfloat16* __restrict__ obf,
                                                 float* __restrict__ of32,
                                                 int ldc, int coff) {
    __shared__ __hip_bfloat16 Alds[128 * LDSS];
    __shared__ __hip_bfloat16 Blds[128 * LDSS];

    int tid = threadIdx.x;
    int wave = tid >> 6, lane = tid & 63;
    int wr = wave >> 1, wc = wave & 1;      // 2x2 wave grid, each wave 64x64
    int quad = lane >> 4, l16 = lane & 15;

    int col0 = blockIdx.x * 128;
    int row0 = blockIdx.y * 128;

    f32x4 acc[4][4] = {};

    int srow = tid >> 2;            // 0..63
    int scol = (tid & 3) * 8;       // 0,8,16,24

    for (int k0 = 0; k0 < K; k0 += 32) {
        __syncthreads();
        for (int half = 0; half < 2; ++half) {
            int r = srow + half * 64;
            int gr = row0 + r;
            uint4 va = make_uint4(0u, 0u, 0u, 0u);
            if (gr < M) va = *(const uint4*)(A + (size_t)gr * lda + k0 + scol);
            *(uint4*)(&Alds[r * LDSS + scol]) = va;
            int gn = col0 + r;
            uint4 vb = *(const uint4*)(Bt + (size_t)gn * K + k0 + scol);
            *(uint4*)(&Blds[r * LDSS + scol]) = vb;
        }
        __syncthreads();

        const __bf16* Ab = (const __bf16*)Alds;
        const __bf16* Bb = (const __bf16*)Blds;
        bf16x8 af[4], bf[4];
#pragma unroll
        for (int mi = 0; mi < 4; ++mi)
            af[mi] = *(const bf16x8*)(Ab + (wr * 64 + mi * 16 + l16) * LDSS + quad * 8);
#pragma unroll
        for (int ni = 0; ni < 4; ++ni)
            bf[ni] = *(const bf16x8*)(Bb + (wc * 64 + ni * 16 + l16) * LDSS + quad * 8);
#pragma unroll
        for (int mi = 0; mi < 4; ++mi)
#pragma unroll
            for (int ni = 0; ni < 4; ++ni)
                acc[mi][ni] = __builtin_amdgcn_mfma_f32_16x16x32_bf16(af[mi], bf[ni],
                                                                      acc[mi][ni], 0, 0, 0);
    }

    // epilogue: C/D layout col = lane&15, row = quad*4 + reg
#pragma unroll
    for (int ni = 0; ni < 4; ++ni) {
        int col = col0 + wc * 64 + ni * 16 + l16;
        float bv = bias[col];
#pragma unroll
        for (int mi = 0; mi < 4; ++mi) {
            int rbase = row0 + wr * 64 + mi * 16 + quad * 4;
#pragma unroll
            for (int r = 0; r < 4; ++r) {
                int row = rbase + r;
                if (row < M) {
                    float v = acc[mi][ni][r] + bv;
                    if (RELU) v = fmaxf(v, 0.f);
                    if (OUT_BF16)
                        obf[(size_t)row * ldc + coff + col] = __float2bfloat16(v);
                    else
                        of32[(size_t)row * ldc + coff + col] = v;
                }
            }
        }
    }
}

// ---------------- launch ----------------

extern "C" void kernel_launch(void* const* d_in, const int* in_sizes, int n_in,
                              void* d_out, int out_size, void* d_ws, size_t ws_size,
                              hipStream_t stream) {
    const float* x   = (const float*)d_in[0];
    const int*   ei  = (const int*)d_in[1];     // int64 in reference -> int32 here
    const float* Wl1 = (const float*)d_in[2];
    const float* bl1 = (const float*)d_in[3];
    const float* Wr1 = (const float*)d_in[4];
    const float* Wl2 = (const float*)d_in[5];
    const float* bl2 = (const float*)d_in[6];
    const float* Wr2 = (const float*)d_in[7];
    const float* Wl3 = (const float*)d_in[8];
    const float* bl3 = (const float*)d_in[9];
    const float* Wr3 = (const float*)d_in[10];
    const float* Wfc = (const float*)d_in[11];
    const float* bfc = (const float*)d_in[12];
    float* out = (float*)d_out;

    const int NN = N_NODES, E = N_EDGES;
    const int NB = (NN + 1023) / 1024;  // 20 scan blocks

    char* p = (char*)d_ws;
    auto alloc = [&](size_t bytes) {
        char* r = p;
        p += (bytes + 511) & ~(size_t)511;
        return r;
    };
    int* cnt   = (int*)alloc((size_t)NN * 4);
    int* off   = (int*)alloc((size_t)(NN + 1) * 4);
    int* cur   = (int*)alloc((size_t)NN * 4);
    int* csr   = (int*)alloc((size_t)E * 4);
    int* bsum  = (int*)alloc((size_t)NB * 4);
    int* carry = (int*)alloc((size_t)NB * 4);
    __hip_bfloat16* Acat1 = (__hip_bfloat16*)alloc((size_t)NN * 512 * 2);   // [mean(x)|x]
    __hip_bfloat16* Acat2 = (__hip_bfloat16*)alloc((size_t)NN * 1024 * 2);  // [mean(h1)|h1]
    __hip_bfloat16* Acat3 = (__hip_bfloat16*)alloc((size_t)NN * 1024 * 2);  // [mean(h2)|h2]
    __hip_bfloat16* Wt1 = (__hip_bfloat16*)alloc((size_t)512 * 512 * 2);
    __hip_bfloat16* Wt2 = (__hip_bfloat16*)alloc((size_t)512 * 1024 * 2);
    __hip_bfloat16* Wt3 = (__hip_bfloat16*)alloc((size_t)1024 * 1024 * 2);
    __hip_bfloat16* Wt4 = (__hip_bfloat16*)alloc((size_t)512 * 1024 * 2);
    __hip_bfloat16* H3 = Acat2;  // alias: Acat2 dead after GEMM2

    // CSR build
    hipMemsetAsync(cnt, 0, (size_t)NN * 4, stream);
    k_count<<<(E + 255) / 256, 256, 0, stream>>>(ei, E, cnt);
    k_scan_block<<<NB, 1024, 0, stream>>>(cnt, off, bsum, NN);
    k_scan_carry<<<1, 64, 0, stream>>>(bsum, carry, NB, off, NN);
    k_scan_add<<<NB, 1024, 0, stream>>>(off, cur, carry, NN);
    k_fill<<<(E + 255) / 256, 256, 0, stream>>>(ei, E, cur, csr);

    // weight transposes (fp32 -> bf16, [K,N] -> [N,Kcat])
    dim3 tb(32, 8);
    k_transpose_w<<<dim3(512 / 32, 256 / 32), tb, 0, stream>>>(Wl1, 256, 512, Wt1, 512, 0);
    k_transpose_w<<<dim3(512 / 32, 256 / 32), tb, 0, stream>>>(Wr1, 256, 512, Wt1, 512, 256);
    k_transpose_w<<<dim3(512 / 32, 512 / 32), tb, 0, stream>>>(Wl2, 512, 512, Wt2, 1024, 0);
    k_transpose_w<<<dim3(512 / 32, 512 / 32), tb, 0, stream>>>(Wr2, 512, 512, Wt2, 1024, 512);
    k_transpose_w<<<dim3(1024 / 32, 512 / 32), tb, 0, stream>>>(Wl3, 512, 1024, Wt3, 1024, 0);
    k_transpose_w<<<dim3(1024 / 32, 512 / 32), tb, 0, stream>>>(Wr3, 512, 1024, Wt3, 1024, 512);
    k_transpose_w<<<dim3(512 / 32, 1024 / 32), tb, 0, stream>>>(Wfc, 1024, 512, Wt4, 1024, 0);

    int mtiles = (NN + 127) / 128;  // 157

    // Layer 1 (agg also converts x -> bf16 right half)
    k_agg_f32<<<NN, 256, 0, stream>>>(x, off, csr, Acat1, 512);
    k_gemm_bt<true, true><<<dim3(4, mtiles), 256, 0, stream>>>(
        Acat1, 512, NN, 512, Wt1, bl1, Acat2, nullptr, 1024, 512);

    // Layer 2
    k_agg_bf16<<<NN, 256, 0, stream>>>(Acat2 + 512, 1024, off, csr, Acat2, 1024);
    k_gemm_bt<true, true><<<dim3(4, mtiles), 256, 0, stream>>>(
        Acat2, 1024, NN, 1024, Wt2, bl2, Acat3, nullptr, 1024, 512);

    // Layer 3 (writes H3 == Acat2; GEMM3 reads only Acat3)
    k_agg_bf16<<<NN, 256, 0, stream>>>(Acat3 + 512, 1024, off, csr, Acat3, 1024);
    k_gemm_bt<true, true><<<dim3(8, mtiles), 256, 0, stream>>>(
        Acat3, 1024, NN, 1024, Wt3, bl3, H3, nullptr, 1024, 0);

    // FC (fp32 out, no relu)
    k_gemm_bt<false, false><<<dim3(4, mtiles), 256, 0, stream>>>(
        H3, 1024, NN, 1024, Wt4, bfc, nullptr, out, 512, 0);
}

// Round 4
// 460.663 us; speedup vs baseline: 1.1767x; 1.1336x over previous
//
#include <hip/hip_runtime.h>
#include <hip/hip_bf16.h>

// MolecularGraphNet: 3x SAGEConv(mean) + Linear, on MI355X.
//  - CSR build on device (int32 edge_index), parallel scan.
//  - Aggregation at the cheap dim with 16 B/lane gathers.
//  - Each SAGE layer = ONE bf16 MFMA GEMM over K-concat [mean | h].
//  - GEMM: 128x128 tile, global_load_lds(16B) staging (m97 structure),
//    XCD-aware block remap (A row-tile pinned to one XCD L2),
//    LDS-staged coalesced epilogue (full-line stores, no partial-line RMW).

typedef __bf16 bf16x8 __attribute__((ext_vector_type(8)));
typedef float  f32x4  __attribute__((ext_vector_type(4)));

#define N_NODES 20000
#define N_EDGES 320000

__device__ __forceinline__ int clampi(int v, int lo, int hi) {
    return v < lo ? lo : (v > hi ? hi : v);
}

__device__ __forceinline__ void load16_lds(const void* g, void* l) {
    __builtin_amdgcn_global_load_lds(
        (const __attribute__((address_space(1))) void*)g,
        (__attribute__((address_space(3))) void*)l, 16, 0, 0);
}

// ---------------- CSR build ----------------

__global__ void k_count(const int* __restrict__ ei, int E, int* __restrict__ cnt) {
    int e = blockIdx.x * blockDim.x + threadIdx.x;
    if (e < E) {
        int dst = clampi(ei[E + e], 0, N_NODES - 1);
        atomicAdd(&cnt[dst], 1);
    }
}

__global__ __launch_bounds__(1024) void k_scan_block(const int* __restrict__ cnt,
                                                     int* __restrict__ off,
                                                     int* __restrict__ bsum, int n) {
    __shared__ int sm[1024];
    int b = blockIdx.x, tid = threadIdx.x;
    int i = b * 1024 + tid;
    int v = (i < n) ? cnt[i] : 0;
    sm[tid] = v;
    __syncthreads();
    for (int s = 1; s < 1024; s <<= 1) {
        int t = (tid >= s) ? sm[tid - s] : 0;
        __syncthreads();
        sm[tid] += t;
        __syncthreads();
    }
    if (i < n) off[i] = sm[tid] - v;
    if (tid == 1023) bsum[b] = sm[1023];
}

__global__ void k_scan_carry(const int* __restrict__ bsum, int* __restrict__ carry,
                             int nb, int* __restrict__ off, int n) {
    if (threadIdx.x == 0 && blockIdx.x == 0) {
        int acc = 0;
        for (int b = 0; b < nb; ++b) { carry[b] = acc; acc += bsum[b]; }
        off[n] = acc;
    }
}

__global__ __launch_bounds__(1024) void k_scan_add(int* __restrict__ off,
                                                   int* __restrict__ cur,
                                                   const int* __restrict__ carry, int n) {
    int i = blockIdx.x * 1024 + threadIdx.x;
    if (i < n) {
        int v = off[i] + carry[blockIdx.x];
        off[i] = v;
        cur[i] = v;
    }
}

__global__ void k_fill(const int* __restrict__ ei, int E,
                       int* __restrict__ cur, int* __restrict__ csr) {
    int e = blockIdx.x * blockDim.x + threadIdx.x;
    if (e < E) {
        int dst = clampi(ei[E + e], 0, N_NODES - 1);
        int src = clampi(ei[e], 0, N_NODES - 1);
        int pos = atomicAdd(&cur[dst], 1);
        if (pos >= 0 && pos < E) csr[pos] = src;
    }
}

// ---------------- weight transpose: W fp32 [K,N] -> Wt bf16 [N, ldt] ----------------

__global__ void k_transpose_w(const float* __restrict__ W, int K, int N,
                              __hip_bfloat16* __restrict__ Wt, int ldt, int koff) {
    __shared__ float tile[32][33];
    int kb = blockIdx.y * 32, nb = blockIdx.x * 32;
    for (int i = 0; i < 32; i += 8) {
        int k = kb + threadIdx.y + i, n = nb + threadIdx.x;
        tile[threadIdx.y + i][threadIdx.x] = W[(size_t)k * N + n];
    }
    __syncthreads();
    for (int i = 0; i < 32; i += 8) {
        int n = nb + threadIdx.y + i, k = kb + threadIdx.x;
        Wt[(size_t)n * ldt + koff + k] = __float2bfloat16(tile[threadIdx.x][threadIdx.y + i]);
    }
}

// ---------------- aggregation (CSR gather, mean) ----------------

__global__ __launch_bounds__(256) void k_agg_f32(const float* __restrict__ xin,
                                                 const int* __restrict__ off,
                                                 const int* __restrict__ csr,
                                                 __hip_bfloat16* __restrict__ outp,
                                                 int ostride) {
    __shared__ float sm[4][256];
    int node = blockIdx.x;
    int tid = threadIdx.x;
    int slot = tid >> 6, lane = tid & 63;
    int c0 = lane * 4;
    int beg = off[node], end = off[node + 1];
    float a0 = 0.f, a1 = 0.f, a2 = 0.f, a3 = 0.f;
    for (int e = beg + slot; e < end; e += 4) {
        int s = csr[e];
        float4 v = *(const float4*)(xin + (size_t)s * 256 + c0);
        a0 += v.x; a1 += v.y; a2 += v.z; a3 += v.w;
    }
    sm[slot][c0] = a0; sm[slot][c0 + 1] = a1; sm[slot][c0 + 2] = a2; sm[slot][c0 + 3] = a3;
    __syncthreads();
    float inv = 1.f / fmaxf((float)(end - beg), 1.f);
    float r = (sm[0][tid] + sm[1][tid]) + (sm[2][tid] + sm[3][tid]);
    outp[(size_t)node * ostride + tid] = __float2bfloat16(r * inv);
    outp[(size_t)node * ostride + 256 + tid] = __float2bfloat16(xin[(size_t)node * 256 + tid]);
}

__global__ __launch_bounds__(256) void k_agg_bf16(const __hip_bfloat16* __restrict__ hin,
                                                  int istride,
                                                  const int* __restrict__ off,
                                                  const int* __restrict__ csr,
                                                  __hip_bfloat16* __restrict__ outp,
                                                  int ostride) {
    __shared__ float sm[4][512];
    int node = blockIdx.x;
    int tid = threadIdx.x;
    int slot = tid >> 6, lane = tid & 63;
    int c0 = lane * 8;
    int beg = off[node], end = off[node + 1];
    float a[8] = {};
    for (int e = beg + slot; e < end; e += 4) {
        int s = csr[e];
        uint4 v = *(const uint4*)(hin + (size_t)s * istride + c0);
        const __hip_bfloat16* hb = (const __hip_bfloat16*)&v;
#pragma unroll
        for (int j = 0; j < 8; ++j) a[j] += __bfloat162float(hb[j]);
    }
#pragma unroll
    for (int j = 0; j < 8; ++j) sm[slot][c0 + j] = a[j];
    __syncthreads();
    float inv = 1.f / fmaxf((float)(end - beg), 1.f);
    int c = tid * 2;
    float r0 = (sm[0][c] + sm[1][c]) + (sm[2][c] + sm[3][c]);
    float r1 = (sm[0][c + 1] + sm[1][c + 1]) + (sm[2][c + 1] + sm[3][c + 1]);
    __hip_bfloat162 o;
    o.x = __float2bfloat16(r0 * inv);
    o.y = __float2bfloat16(r1 * inv);
    *(__hip_bfloat162*)(outp + (size_t)node * ostride + c) = o;
}

// ---------------- bf16 MFMA GEMM: C = act(A @ Bt^T + bias) ----------------
// A: [M,K] bf16 row-major; Bt: [N,K] bf16 row-major; N % 128 == 0, K % 32 == 0.
// 1D grid with XCD remap: xcd = bid&7; within an XCD, col-tiles vary fastest so
// each A row-tile is fetched into exactly one XCD's L2.

#define SMEM_BYTES 34816

template <bool RELU, bool OUT_BF16>
__global__ __launch_bounds__(256) void k_gemm_bt(const __hip_bfloat16* __restrict__ A,
                                                 int lda, int M, int K,
                                                 const __hip_bfloat16* __restrict__ Bt,
                                                 const float* __restrict__ bias,
                                                 __hip_bfloat16* __restrict__ obf,
                                                 float* __restrict__ of32,
                                                 int ldc, int coff,
                                                 int rtiles, int ctlog2) {
    __shared__ char smem[SMEM_BYTES];
    __bf16* Alds = (__bf16*)smem;             // 128 rows x 32 (contiguous, 64 B rows)
    __bf16* Blds = (__bf16*)(smem + 8192);    // 128 rows x 32

    int bid = blockIdx.x;
    int xcd = bid & 7, local = bid >> 3;
    int cmask = (1 << ctlog2) - 1;
    int colTile = local & cmask;
    int rowTile = (local >> ctlog2) * 8 + xcd;
    if (rowTile >= rtiles) return;
    int row0 = rowTile * 128, col0 = colTile * 128;

    int tid = threadIdx.x;
    int wave = tid >> 6, lane = tid & 63;
    int wr = wave >> 1, wc = wave & 1;
    int quad = lane >> 4, l16 = lane & 15;

    // async staging: each wave stages 32 rows of A and 32 rows of B per K-step
    int rlo = lane >> 2, ch = lane & 3;
    int ra0 = clampi(row0 + wave * 32 + rlo, 0, M - 1);
    int ra1 = clampi(row0 + wave * 32 + 16 + rlo, 0, M - 1);
    const __hip_bfloat16* gA0 = A + (size_t)ra0 * lda + ch * 8;
    const __hip_bfloat16* gA1 = A + (size_t)ra1 * lda + ch * 8;
    const __hip_bfloat16* gB0 = Bt + (size_t)(col0 + wave * 32 + rlo) * K + ch * 8;
    const __hip_bfloat16* gB1 = gB0 + (size_t)16 * K;
    __bf16* lA0 = Alds + (wave * 32) * 32;
    __bf16* lA1 = Alds + (wave * 32 + 16) * 32;
    __bf16* lB0 = Blds + (wave * 32) * 32;
    __bf16* lB1 = Blds + (wave * 32 + 16) * 32;

    f32x4 acc[4][4] = {};

    for (int k0 = 0; k0 < K; k0 += 32) {
        __syncthreads();
        load16_lds(gA0 + k0, lA0);
        load16_lds(gA1 + k0, lA1);
        load16_lds(gB0 + k0, lB0);
        load16_lds(gB1 + k0, lB1);
        __syncthreads();

        bf16x8 af[4], bf[4];
#pragma unroll
        for (int mi = 0; mi < 4; ++mi)
            af[mi] = *(const bf16x8*)(Alds + (wr * 64 + mi * 16 + l16) * 32 + quad * 8);
#pragma unroll
        for (int ni = 0; ni < 4; ++ni)
            bf[ni] = *(const bf16x8*)(Blds + (wc * 64 + ni * 16 + l16) * 32 + quad * 8);
#pragma unroll
        for (int mi = 0; mi < 4; ++mi)
#pragma unroll
            for (int ni = 0; ni < 4; ++ni)
                acc[mi][ni] = __builtin_amdgcn_mfma_f32_16x16x32_bf16(af[mi], bf[ni],
                                                                      acc[mi][ni], 0, 0, 0);
    }

    // ---------- coalesced epilogue through LDS ----------
    // C/D layout: col = l16, row = quad*4 + reg
    __syncthreads();  // all frag reads done; smem is now free
    if (OUT_BF16) {
        __bf16* cb = (__bf16*)smem;  // [128][136] bf16 (row = 272 B, 16B-aligned)
#pragma unroll
        for (int ni = 0; ni < 4; ++ni) {
            int ct = wc * 64 + ni * 16 + l16;
            float bv = bias[col0 + ct];
#pragma unroll
            for (int mi = 0; mi < 4; ++mi) {
                int rb = wr * 64 + mi * 16 + quad * 4;
#pragma unroll
                for (int r = 0; r < 4; ++r) {
                    float v = acc[mi][ni][r] + bv;
                    if (RELU) v = fmaxf(v, 0.f);
                    cb[(rb + r) * 136 + ct] = (__bf16)v;
                }
            }
        }
        __syncthreads();
        int chunk = tid & 15;           // 16 chunks x 8 bf16 = 128 cols
        int rl = tid >> 4;              // 16 rows per pass
#pragma unroll
        for (int p = 0; p < 8; ++p) {
            int rt = p * 16 + rl;
            int row = row0 + rt;
            if (row < M) {
                uint4 v = *(const uint4*)(cb + rt * 136 + chunk * 8);
                *(uint4*)(obf + (size_t)row * ldc + coff + col0 + chunk * 8) = v;
            }
        }
    } else {
        float* cf = (float*)smem;       // [128][68] fp32, two 64-col halves
#pragma unroll
        for (int h = 0; h < 2; ++h) {
            if (wc == h) {
#pragma unroll
                for (int ni = 0; ni < 4; ++ni) {
                    int ctl = ni * 16 + l16;   // col within half
                    float bv = bias[col0 + h * 64 + ctl];
#pragma unroll
                    for (int mi = 0; mi < 4; ++mi) {
                        int rb = wr * 64 + mi * 16 + quad * 4;
#pragma unroll
                        for (int r = 0; r < 4; ++r) {
                            float v = acc[mi][ni][r] + bv;
                            if (RELU) v = fmaxf(v, 0.f);
                            cf[(rb + r) * 68 + ctl] = v;
                        }
                    }
                }
            }
            __syncthreads();
            int chunk = tid & 15;       // 16 chunks x 4 fp32 = 64 cols
            int rl = tid >> 4;
#pragma unroll
            for (int p = 0; p < 8; ++p) {
                int rt = p * 16 + rl;
                int row = row0 + rt;
                if (row < M) {
                    float4 v = *(const float4*)(cf + rt * 68 + chunk * 4);
                    *(float4*)(of32 + (size_t)row * ldc + col0 + h * 64 + chunk * 4) = v;
                }
            }
            __syncthreads();
        }
    }
}

// ---------------- launch ----------------

extern "C" void kernel_launch(void* const* d_in, const int* in_sizes, int n_in,
                              void* d_out, int out_size, void* d_ws, size_t ws_size,
                              hipStream_t stream) {
    const float* x   = (const float*)d_in[0];
    const int*   ei  = (const int*)d_in[1];
    const float* Wl1 = (const float*)d_in[2];
    const float* bl1 = (const float*)d_in[3];
    const float* Wr1 = (const float*)d_in[4];
    const float* Wl2 = (const float*)d_in[5];
    const float* bl2 = (const float*)d_in[6];
    const float* Wr2 = (const float*)d_in[7];
    const float* Wl3 = (const float*)d_in[8];
    const float* bl3 = (const float*)d_in[9];
    const float* Wr3 = (const float*)d_in[10];
    const float* Wfc = (const float*)d_in[11];
    const float* bfc = (const float*)d_in[12];
    float* out = (float*)d_out;

    const int NN = N_NODES, E = N_EDGES;
    const int NB = (NN + 1023) / 1024;

    char* p = (char*)d_ws;
    auto alloc = [&](size_t bytes) {
        char* r = p;
        p += (bytes + 511) & ~(size_t)511;
        return r;
    };
    int* cnt   = (int*)alloc((size_t)NN * 4);
    int* off   = (int*)alloc((size_t)(NN + 1) * 4);
    int* cur   = (int*)alloc((size_t)NN * 4);
    int* csr   = (int*)alloc((size_t)E * 4);
    int* bsum  = (int*)alloc((size_t)NB * 4);
    int* carry = (int*)alloc((size_t)NB * 4);
    __hip_bfloat16* Acat1 = (__hip_bfloat16*)alloc((size_t)NN * 512 * 2);
    __hip_bfloat16* Acat2 = (__hip_bfloat16*)alloc((size_t)NN * 1024 * 2);
    __hip_bfloat16* Acat3 = (__hip_bfloat16*)alloc((size_t)NN * 1024 * 2);
    __hip_bfloat16* Wt1 = (__hip_bfloat16*)alloc((size_t)512 * 512 * 2);
    __hip_bfloat16* Wt2 = (__hip_bfloat16*)alloc((size_t)512 * 1024 * 2);
    __hip_bfloat16* Wt3 = (__hip_bfloat16*)alloc((size_t)1024 * 1024 * 2);
    __hip_bfloat16* Wt4 = (__hip_bfloat16*)alloc((size_t)512 * 1024 * 2);
    __hip_bfloat16* H3 = Acat2;  // alias: Acat2 dead after GEMM2

    // CSR build
    hipMemsetAsync(cnt, 0, (size_t)NN * 4, stream);
    k_count<<<(E + 255) / 256, 256, 0, stream>>>(ei, E, cnt);
    k_scan_block<<<NB, 1024, 0, stream>>>(cnt, off, bsum, NN);
    k_scan_carry<<<1, 64, 0, stream>>>(bsum, carry, NB, off, NN);
    k_scan_add<<<NB, 1024, 0, stream>>>(off, cur, carry, NN);
    k_fill<<<(E + 255) / 256, 256, 0, stream>>>(ei, E, cur, csr);

    // weight transposes
    dim3 tb(32, 8);
    k_transpose_w<<<dim3(512 / 32, 256 / 32), tb, 0, stream>>>(Wl1, 256, 512, Wt1, 512, 0);
    k_transpose_w<<<dim3(512 / 32, 256 / 32), tb, 0, stream>>>(Wr1, 256, 512, Wt1, 512, 256);
    k_transpose_w<<<dim3(512 / 32, 512 / 32), tb, 0, stream>>>(Wl2, 512, 512, Wt2, 1024, 0);
    k_transpose_w<<<dim3(512 / 32, 512 / 32), tb, 0, stream>>>(Wr2, 512, 512, Wt2, 1024, 512);
    k_transpose_w<<<dim3(1024 / 32, 512 / 32), tb, 0, stream>>>(Wl3, 512, 1024, Wt3, 1024, 0);
    k_transpose_w<<<dim3(1024 / 32, 512 / 32), tb, 0, stream>>>(Wr3, 512, 1024, Wt3, 1024, 512);
    k_transpose_w<<<dim3(512 / 32, 1024 / 32), tb, 0, stream>>>(Wfc, 1024, 512, Wt4, 1024, 0);

    int rtiles = (NN + 127) / 128;              // 157
    int rg = ((rtiles + 7) / 8) * 8;            // 160 (padded row-tile groups)

    // Layer 1 (agg also converts x -> bf16 right half)
    k_agg_f32<<<NN, 256, 0, stream>>>(x, off, csr, Acat1, 512);
    k_gemm_bt<true, true><<<rg * 4, 256, 0, stream>>>(
        Acat1, 512, NN, 512, Wt1, bl1, Acat2, nullptr, 1024, 512, rtiles, 2);

    // Layer 2
    k_agg_bf16<<<NN, 256, 0, stream>>>(Acat2 + 512, 1024, off, csr, Acat2, 1024);
    k_gemm_bt<true, true><<<rg * 4, 256, 0, stream>>>(
        Acat2, 1024, NN, 1024, Wt2, bl2, Acat3, nullptr, 1024, 512, rtiles, 2);

    // Layer 3 (writes H3 == Acat2; GEMM3 reads only Acat3)
    k_agg_bf16<<<NN, 256, 0, stream>>>(Acat3 + 512, 1024, off, csr, Acat3, 1024);
    k_gemm_bt<true, true><<<rg * 8, 256, 0, stream>>>(
        Acat3, 1024, NN, 1024, Wt3, bl3, H3, nullptr, 1024, 0, rtiles, 3);

    // FC (fp32 out, no relu)
    k_gemm_bt<false, false><<<rg * 4, 256, 0, stream>>>(
        H3, 1024, NN, 1024, Wt4, bfc, nullptr, out, 512, 0, rtiles, 2);
}

// Round 5
// 446.410 us; speedup vs baseline: 1.2143x; 1.0319x over previous
//
#include <hip/hip_runtime.h>
#include <hip/hip_bf16.h>

// MolecularGraphNet: 3x SAGEConv(mean) + Linear, on MI355X.
//  - GEMM operands in chunk-linear swizzled format:
//      elem(r,k) of [rows,K] at (r>>7)*(K*128) + (k>>3)*1024 + (r&127)*8 + (k&7)
//    => one K64-stage of a 128-row tile is a contiguous 16 KB block (global_load_lds).
//  - GEMM: 128x128 tile, BK=64 (16 barrier-pairs at K=1024), XCD-aware remap,
//    dual-store epilogue (swizzled for next GEMM + row-major for agg gather).
//  - Aggregation gathers from row-major h copies (16 B/lane), writes swizzled mean.

typedef __bf16 bf16x8 __attribute__((ext_vector_type(8)));
typedef float  f32x4  __attribute__((ext_vector_type(4)));

#define N_NODES 20000
#define N_EDGES 320000
#define MPAD 20096   // 157*128

__device__ __forceinline__ int clampi(int v, int lo, int hi) {
    return v < lo ? lo : (v > hi ? hi : v);
}

__device__ __forceinline__ void load16_lds(const void* g, void* l) {
    __builtin_amdgcn_global_load_lds(
        (const __attribute__((address_space(1))) void*)g,
        (__attribute__((address_space(3))) void*)l, 16, 0, 0);
}

// ---------------- CSR build ----------------

__global__ void k_count(const int* __restrict__ ei, int E, int* __restrict__ cnt) {
    int e = blockIdx.x * blockDim.x + threadIdx.x;
    if (e < E) atomicAdd(&cnt[clampi(ei[E + e], 0, N_NODES - 1)], 1);
}

__global__ __launch_bounds__(1024) void k_scan_block(const int* __restrict__ cnt,
                                                     int* __restrict__ off,
                                                     int* __restrict__ bsum, int n) {
    __shared__ int sm[1024];
    int b = blockIdx.x, tid = threadIdx.x;
    int i = b * 1024 + tid;
    int v = (i < n) ? cnt[i] : 0;
    sm[tid] = v;
    __syncthreads();
    for (int s = 1; s < 1024; s <<= 1) {
        int t = (tid >= s) ? sm[tid - s] : 0;
        __syncthreads();
        sm[tid] += t;
        __syncthreads();
    }
    if (i < n) off[i] = sm[tid] - v;
    if (tid == 1023) bsum[b] = sm[1023];
}

__global__ void k_scan_carry(const int* __restrict__ bsum, int* __restrict__ carry,
                             int nb, int* __restrict__ off, int n) {
    if (threadIdx.x == 0 && blockIdx.x == 0) {
        int acc = 0;
        for (int b = 0; b < nb; ++b) { carry[b] = acc; acc += bsum[b]; }
        off[n] = acc;
    }
}

__global__ __launch_bounds__(1024) void k_scan_add(int* __restrict__ off,
                                                   int* __restrict__ cur,
                                                   const int* __restrict__ carry, int n) {
    int i = blockIdx.x * 1024 + threadIdx.x;
    if (i < n) {
        int v = off[i] + carry[blockIdx.x];
        off[i] = v;
        cur[i] = v;
    }
}

__global__ void k_fill(const int* __restrict__ ei, int E,
                       int* __restrict__ cur, int* __restrict__ csr) {
    int e = blockIdx.x * blockDim.x + threadIdx.x;
    if (e < E) {
        int dst = clampi(ei[E + e], 0, N_NODES - 1);
        int src = clampi(ei[e], 0, N_NODES - 1);
        int pos = atomicAdd(&cur[dst], 1);
        if (pos >= 0 && pos < E) csr[pos] = src;
    }
}

// ---------------- fused weight transposes: W fp32 [K,N] -> swizzled bf16 [N,KT] ----------------

struct TDesc { const float* W; __bf16* Wt; int K, N, KT, koff, tile0; };
struct TDescs { TDesc d[7]; };

__global__ void k_transpose_all(TDescs ds) {
    __shared__ float tile[32][33];
    int b = blockIdx.x;
    int di = 0;
#pragma unroll
    for (int i = 1; i < 7; ++i)
        if (b >= ds.d[i].tile0) di = i;
    const float* W = ds.d[di].W;
    __bf16* Wt = ds.d[di].Wt;
    int N = ds.d[di].N, KT = ds.d[di].KT, koff = ds.d[di].koff;
    int t = b - ds.d[di].tile0;
    int ntn = N >> 5;
    int nb = (t % ntn) * 32, kb = (t / ntn) * 32;
    for (int i = 0; i < 32; i += 8) {
        int k = kb + threadIdx.y + i, n = nb + threadIdx.x;
        tile[threadIdx.y + i][threadIdx.x] = W[(size_t)k * N + n];
    }
    __syncthreads();
    for (int i = 0; i < 32; i += 8) {
        int n = nb + threadIdx.y + i, k = koff + kb + threadIdx.x;
        size_t o = (size_t)(n >> 7) * ((size_t)KT * 128) + (size_t)(k >> 3) * 1024 +
                   (size_t)((n & 127) * 8) + (k & 7);
        Wt[o] = (__bf16)tile[threadIdx.x][threadIdx.y + i];
    }
}

// ---------------- aggregation (CSR gather, mean) ----------------

// layer 1: gathers fp32 x rows; writes mean (chunks 0..31) + x bf16 (chunks 32..63)
// into swizzled Acat1 (K=512).
__global__ __launch_bounds__(256) void k_agg_f32(const float* __restrict__ xin,
                                                 const int* __restrict__ off,
                                                 const int* __restrict__ csr,
                                                 __bf16* __restrict__ acat) {
    __shared__ float sm[4][256];
    int node = blockIdx.x;
    int tid = threadIdx.x, slot = tid >> 6, lane = tid & 63;
    int c0 = lane * 4;
    int beg = off[node], end = off[node + 1];
    float a0 = 0.f, a1 = 0.f, a2 = 0.f, a3 = 0.f;
    for (int e = beg + slot; e < end; e += 4) {
        int s = csr[e];
        float4 v = *(const float4*)(xin + (size_t)s * 256 + c0);
        a0 += v.x; a1 += v.y; a2 += v.z; a3 += v.w;
    }
    sm[slot][c0] = a0; sm[slot][c0 + 1] = a1; sm[slot][c0 + 2] = a2; sm[slot][c0 + 3] = a3;
    __syncthreads();
    __bf16* base = acat + (size_t)(node >> 7) * (512 * 128) + (size_t)((node & 127) * 8);
    if (tid < 32) {
        float inv = 1.f / fmaxf((float)(end - beg), 1.f);
        int c = tid;
        __bf16 tmp[8];
#pragma unroll
        for (int i = 0; i < 8; ++i) {
            int col = c * 8 + i;
            tmp[i] = (__bf16)((sm[0][col] + sm[1][col] + sm[2][col] + sm[3][col]) * inv);
        }
        *(uint4*)(base + (size_t)c * 1024) = *(const uint4*)tmp;
    } else if (tid >= 64 && tid < 96) {
        int c = tid - 64;
        float4 u = *(const float4*)(xin + (size_t)node * 256 + c * 8);
        float4 w = *(const float4*)(xin + (size_t)node * 256 + c * 8 + 4);
        __bf16 tmp[8] = {(__bf16)u.x, (__bf16)u.y, (__bf16)u.z, (__bf16)u.w,
                         (__bf16)w.x, (__bf16)w.y, (__bf16)w.z, (__bf16)w.w};
        *(uint4*)(base + (size_t)(32 + c) * 1024) = *(const uint4*)tmp;
    }
}

// layers 2/3: gathers bf16 rows from ROW-MAJOR h copy [MPAD,512];
// writes mean into swizzled Acat (chunks 0..63 of width Kc=1024).
__global__ __launch_bounds__(256) void k_agg_bf16(const __hip_bfloat16* __restrict__ hrm,
                                                  const int* __restrict__ off,
                                                  const int* __restrict__ csr,
                                                  __bf16* __restrict__ acat) {
    __shared__ float sm[4][512];
    int node = blockIdx.x;
    int tid = threadIdx.x, slot = tid >> 6, lane = tid & 63;
    int c0 = lane * 8;
    int beg = off[node], end = off[node + 1];
    float a[8] = {};
    for (int e = beg + slot; e < end; e += 4) {
        int s = csr[e];
        uint4 v = *(const uint4*)(hrm + (size_t)s * 512 + c0);
        const __hip_bfloat16* hb = (const __hip_bfloat16*)&v;
#pragma unroll
        for (int j = 0; j < 8; ++j) a[j] += __bfloat162float(hb[j]);
    }
#pragma unroll
    for (int j = 0; j < 8; ++j) sm[slot][c0 + j] = a[j];
    __syncthreads();
    if (tid < 64) {
        float inv = 1.f / fmaxf((float)(end - beg), 1.f);
        int c = tid;
        __bf16 tmp[8];
#pragma unroll
        for (int i = 0; i < 8; ++i) {
            int col = c * 8 + i;
            tmp[i] = (__bf16)((sm[0][col] + sm[1][col] + sm[2][col] + sm[3][col]) * inv);
        }
        *(uint4*)(acat + (size_t)(node >> 7) * (1024 * 128) +
                  (size_t)((node & 127) * 8) + (size_t)c * 1024) = *(const uint4*)tmp;
    }
}

// ---------------- bf16 MFMA GEMM, swizzled operands ----------------
// OUTMODE: 0 = bf16 swizzled; 1 = bf16 swizzled + row-major copy; 2 = fp32 row-major.

template <bool RELU, int OUTMODE>
__global__ __launch_bounds__(256) void k_gemm(const __bf16* __restrict__ A, int K, int M,
                                              const __bf16* __restrict__ B,
                                              const float* __restrict__ bias,
                                              __bf16* __restrict__ osw, int Kc, int coff,
                                              __bf16* __restrict__ orm, int ldrm,
                                              float* __restrict__ of32, int ldf,
                                              int rtiles, int ctlog2) {
    constexpr int SMEM = (OUTMODE == 2) ? 34816 : 32768;
    __shared__ char smem[SMEM];
    __bf16* Alds = (__bf16*)smem;             // [2 sub-panels][4 chunks][128 rows][8]
    __bf16* Blds = (__bf16*)(smem + 16384);

    int bid = blockIdx.x;
    int xcd = bid & 7, local = bid >> 3;
    int cmask = (1 << ctlog2) - 1;
    int colTile = local & cmask;
    int rowTile = (local >> ctlog2) * 8 + xcd;
    if (rowTile >= rtiles) return;

    const __bf16* Atile = A + (size_t)rowTile * ((size_t)K * 128);
    const __bf16* Btile = B + (size_t)colTile * ((size_t)K * 128);

    int tid = threadIdx.x;
    int wave = tid >> 6, lane = tid & 63;
    int wr = wave >> 1, wc = wave & 1;
    int quad = lane >> 4, l16 = lane & 15;

    f32x4 acc[4][4] = {};

    for (int k0 = 0; k0 < K; k0 += 64) {
        __syncthreads();
        const __bf16* gA = Atile + (size_t)k0 * 128;   // contiguous 16 KB stage
        const __bf16* gB = Btile + (size_t)k0 * 128;
#pragma unroll
        for (int j = 0; j < 4; ++j) {
            int slot = (j * 256 + tid) * 8;
            load16_lds(gA + slot, Alds + slot);
            load16_lds(gB + slot, Blds + slot);
        }
        __syncthreads();
#pragma unroll
        for (int sp = 0; sp < 2; ++sp) {
            bf16x8 af[4], bf[4];
#pragma unroll
            for (int mi = 0; mi < 4; ++mi)
                af[mi] = *(const bf16x8*)(Alds + sp * 4096 + quad * 1024 +
                                          (wr * 64 + mi * 16 + l16) * 8);
#pragma unroll
            for (int ni = 0; ni < 4; ++ni)
                bf[ni] = *(const bf16x8*)(Blds + sp * 4096 + quad * 1024 +
                                          (wc * 64 + ni * 16 + l16) * 8);
#pragma unroll
            for (int mi = 0; mi < 4; ++mi)
#pragma unroll
                for (int ni = 0; ni < 4; ++ni)
                    acc[mi][ni] = __builtin_amdgcn_mfma_f32_16x16x32_bf16(
                        af[mi], bf[ni], acc[mi][ni], 0, 0, 0);
        }
    }

    int col0 = colTile * 128;
    int row0 = rowTile * 128;
    __syncthreads();   // frag reads done; smem free for epilogue

    if (OUTMODE != 2) {
        // stage C chunk-major [16 chunks][128 rows][8] = 32 KB
        __bf16* cb = (__bf16*)smem;
#pragma unroll
        for (int ni = 0; ni < 4; ++ni) {
            int ct = wc * 64 + ni * 16 + l16;
            float bv = bias[col0 + ct];
#pragma unroll
            for (int mi = 0; mi < 4; ++mi) {
                int rb = wr * 64 + mi * 16 + quad * 4;
#pragma unroll
                for (int r = 0; r < 4; ++r) {
                    float v = acc[mi][ni][r] + bv;
                    if (RELU) v = fmaxf(v, 0.f);
                    cb[(ct >> 3) * 1024 + (rb + r) * 8 + (ct & 7)] = (__bf16)v;
                }
            }
        }
        __syncthreads();
        // swizzled store: one contiguous 32 KB region (padded rows -> no guard)
        __bf16* dst = osw + (size_t)rowTile * ((size_t)Kc * 128) +
                      (size_t)((coff + col0) >> 3) * 1024;
#pragma unroll
        for (int p2 = 0; p2 < 8; ++p2) {
            int idx = (p2 * 256 + tid) * 8;
            *(uint4*)(dst + idx) = *(const uint4*)(cb + idx);
        }
        if (OUTMODE == 1) {
            // row-major copy for the aggregation gather (padded rows -> no guard)
#pragma unroll
            for (int p2 = 0; p2 < 8; ++p2) {
                int rr = p2 * 16 + (tid >> 4);
                int cc = tid & 15;
                *(uint4*)(orm + (size_t)(row0 + rr) * ldrm + col0 + cc * 8) =
                    *(const uint4*)(cb + cc * 1024 + rr * 8);
            }
        }
    } else {
        float* cf = (float*)smem;   // [128][68] fp32, two 64-col halves
#pragma unroll
        for (int h = 0; h < 2; ++h) {
            if (wc == h) {
#pragma unroll
                for (int ni = 0; ni < 4; ++ni) {
                    int ctl = ni * 16 + l16;
                    float bv = bias[col0 + h * 64 + ctl];
#pragma unroll
                    for (int mi = 0; mi < 4; ++mi) {
                        int rb = wr * 64 + mi * 16 + quad * 4;
#pragma unroll
                        for (int r = 0; r < 4; ++r) {
                            float v = acc[mi][ni][r] + bv;
                            if (RELU) v = fmaxf(v, 0.f);
                            cf[(rb + r) * 68 + ctl] = v;
                        }
                    }
                }
            }
            __syncthreads();
            int chunk = tid & 15, rl = tid >> 4;
#pragma unroll
            for (int p2 = 0; p2 < 8; ++p2) {
                int rt = p2 * 16 + rl;
                int row = row0 + rt;
                if (row < M) {
                    float4 v = *(const float4*)(cf + rt * 68 + chunk * 4);
                    *(float4*)(of32 + (size_t)row * ldf + col0 + h * 64 + chunk * 4) = v;
                }
            }
            __syncthreads();
        }
    }
}

// ---------------- launch ----------------

extern "C" void kernel_launch(void* const* d_in, const int* in_sizes, int n_in,
                              void* d_out, int out_size, void* d_ws, size_t ws_size,
                              hipStream_t stream) {
    const float* x   = (const float*)d_in[0];
    const int*   ei  = (const int*)d_in[1];
    const float* Wl1 = (const float*)d_in[2];
    const float* bl1 = (const float*)d_in[3];
    const float* Wr1 = (const float*)d_in[4];
    const float* Wl2 = (const float*)d_in[5];
    const float* bl2 = (const float*)d_in[6];
    const float* Wr2 = (const float*)d_in[7];
    const float* Wl3 = (const float*)d_in[8];
    const float* bl3 = (const float*)d_in[9];
    const float* Wr3 = (const float*)d_in[10];
    const float* Wfc = (const float*)d_in[11];
    const float* bfc = (const float*)d_in[12];
    float* out = (float*)d_out;

    const int NN = N_NODES, E = N_EDGES;
    const int NB = (NN + 1023) / 1024;

    char* p = (char*)d_ws;
    auto alloc = [&](size_t bytes) {
        char* r = p;
        p += (bytes + 511) & ~(size_t)511;
        return r;
    };
    int* cnt   = (int*)alloc((size_t)NN * 4);
    int* off   = (int*)alloc((size_t)(NN + 1) * 4);
    int* cur   = (int*)alloc((size_t)NN * 4);
    int* csr   = (int*)alloc((size_t)E * 4);
    int* bsum  = (int*)alloc((size_t)NB * 4);
    int* carry = (int*)alloc((size_t)NB * 4);
    __bf16* Acat1 = (__bf16*)alloc((size_t)MPAD * 512 * 2);    // swz [mean|x], K=512
    __bf16* Acat2 = (__bf16*)alloc((size_t)MPAD * 1024 * 2);   // swz [mean|h1], K=1024
    __bf16* Acat3 = (__bf16*)alloc((size_t)MPAD * 1024 * 2);   // swz [mean|h2], K=1024
    __bf16* Hrm   = (__bf16*)alloc((size_t)MPAD * 512 * 2);    // row-major h1, then h2
    __bf16* Wt1 = (__bf16*)alloc((size_t)512 * 512 * 2);
    __bf16* Wt2 = (__bf16*)alloc((size_t)512 * 1024 * 2);
    __bf16* Wt3 = (__bf16*)alloc((size_t)1024 * 1024 * 2);
    __bf16* Wt4 = (__bf16*)alloc((size_t)512 * 1024 * 2);
    __bf16* H3 = Acat2;   // alias: Acat2 dead after GEMM2 reads it

    // CSR build
    hipMemsetAsync(cnt, 0, (size_t)NN * 4, stream);
    k_count<<<(E + 255) / 256, 256, 0, stream>>>(ei, E, cnt);
    k_scan_block<<<NB, 1024, 0, stream>>>(cnt, off, bsum, NN);
    k_scan_carry<<<1, 64, 0, stream>>>(bsum, carry, NB, off, NN);
    k_scan_add<<<NB, 1024, 0, stream>>>(off, cur, carry, NN);
    k_fill<<<(E + 255) / 256, 256, 0, stream>>>(ei, E, cur, csr);

    // fused weight transposes (tile counts: 128,128,256,256,512,512,512 = 2304)
    TDescs td;
    td.d[0] = {Wl1, Wt1, 256, 512, 512, 0, 0};
    td.d[1] = {Wr1, Wt1, 256, 512, 512, 256, 128};
    td.d[2] = {Wl2, Wt2, 512, 512, 1024, 0, 256};
    td.d[3] = {Wr2, Wt2, 512, 512, 1024, 512, 512};
    td.d[4] = {Wl3, Wt3, 512, 1024, 1024, 0, 768};
    td.d[5] = {Wr3, Wt3, 512, 1024, 1024, 512, 1280};
    td.d[6] = {Wfc, Wt4, 1024, 512, 1024, 0, 1792};
    k_transpose_all<<<2304, dim3(32, 8), 0, stream>>>(td);

    int rtiles = (NN + 127) / 128;        // 157
    int rg = ((rtiles + 7) / 8) * 8;      // 160

    // Layer 1
    k_agg_f32<<<NN, 256, 0, stream>>>(x, off, csr, Acat1);
    k_gemm<true, 1><<<rg * 4, 256, 0, stream>>>(
        Acat1, 512, NN, Wt1, bl1, Acat2, 1024, 512, Hrm, 512, nullptr, 0, rtiles, 2);

    // Layer 2
    k_agg_bf16<<<NN, 256, 0, stream>>>((const __hip_bfloat16*)Hrm, off, csr, Acat2);
    k_gemm<true, 1><<<rg * 4, 256, 0, stream>>>(
        Acat2, 1024, NN, Wt2, bl2, Acat3, 1024, 512, Hrm, 512, nullptr, 0, rtiles, 2);

    // Layer 3 (writes H3 == Acat2 swizzled only; FC reads it swizzled)
    k_agg_bf16<<<NN, 256, 0, stream>>>((const __hip_bfloat16*)Hrm, off, csr, Acat3);
    k_gemm<true, 0><<<rg * 8, 256, 0, stream>>>(
        Acat3, 1024, NN, Wt3, bl3, H3, 1024, 0, nullptr, 0, nullptr, 0, rtiles, 3);

    // FC (fp32 row-major out, no relu)
    k_gemm<false, 2><<<rg * 4, 256, 0, stream>>>(
        H3, 1024, NN, Wt4, bfc, nullptr, 0, 0, nullptr, 0, out, 512, rtiles, 2);
}